// Round 1
// baseline (270.401 us; speedup 1.0000x reference)
//
#include <hip/hip_runtime.h>

// NCA update step, fp32 baseline.
// x:     [B=4, C=16, H=512, W=512] fp32
// noise: [B, 1, H, W] fp32
// w1_w:  [HID=192, 2C=32] fp32, w1_b: [192], w2_w: [C=16, HID=192]
// out:   [B, C, H, W] fp32
//
// out = (x + dx * floor(noise+0.5)) * alive
//   y = [x, 8x - sum8(x)] (circular), h = relu(W1 y + b), dx = W2 h
//   alive = (maxpool3x3_circ(x[:,3]) > 0.1)

#define BB   4
#define CC   16
#define HH   512
#define WW   512
#define HWSZ (HH * WW)
#define HID  192
#define PERC 32

__global__ __launch_bounds__(256) void nca_fp32_kernel(
    const float* __restrict__ x,
    const float* __restrict__ noise,
    const float* __restrict__ w1w,
    const float* __restrict__ w1b,
    const float* __restrict__ w2w,
    float* __restrict__ out)
{
    const int p = blockIdx.x * blockDim.x + threadIdx.x;   // global pixel id
    if (p >= BB * HWSZ) return;
    const int b   = p / HWSZ;
    const int rem = p - b * HWSZ;
    const int i   = rem / WW;
    const int j   = rem - i * WW;

    // circular neighbors
    const int im = (i == 0)      ? HH - 1 : i - 1;
    const int ip = (i == HH - 1) ? 0      : i + 1;
    const int jm = (j == 0)      ? WW - 1 : j - 1;
    const int jp = (j == WW - 1) ? 0      : j + 1;

    const int rm = im * WW, r0 = i * WW, rp = ip * WW;

    float y[2 * CC];
    float amax = -1e30f;

    const float* xb = x + (size_t)b * CC * HWSZ;
    #pragma unroll
    for (int c = 0; c < CC; ++c) {
        const float* xc = xb + c * HWSZ;
        const float v00 = xc[rm + jm], v01 = xc[rm + j], v02 = xc[rm + jp];
        const float v10 = xc[r0 + jm], v11 = xc[r0 + j], v12 = xc[r0 + jp];
        const float v20 = xc[rp + jm], v21 = xc[rp + j], v22 = xc[rp + jp];
        const float s8 = ((v00 + v01) + (v02 + v10)) +
                         ((v12 + v20) + (v21 + v22));
        y[c]      = v11;
        y[CC + c] = 8.0f * v11 - s8;
        if (c == 3) {
            float m = fmaxf(fmaxf(fmaxf(v00, v01), fmaxf(v02, v10)),
                            fmaxf(fmaxf(v11, v12), fmaxf(v20, fmaxf(v21, v22))));
            amax = m;
        }
    }

    const float alive = (amax > 0.1f) ? 1.0f : 0.0f;
    const float umask = floorf(noise[(size_t)b * HWSZ + rem] + 0.5f);

    float dx[CC];
    #pragma unroll
    for (int k = 0; k < CC; ++k) dx[k] = 0.0f;

    // MLP: weights are wave-uniform -> compiler should emit s_load + SGPR-operand FMAs
    #pragma unroll 4
    for (int o = 0; o < HID; ++o) {
        float acc = w1b[o];
        #pragma unroll
        for (int c = 0; c < 2 * CC; ++c)
            acc = fmaf(w1w[o * PERC + c], y[c], acc);
        const float h = fmaxf(acc, 0.0f);
        #pragma unroll
        for (int k = 0; k < CC; ++k)
            dx[k] = fmaf(w2w[k * HID + o], h, dx[k]);
    }

    float* ob = out + (size_t)b * CC * HWSZ + rem;
    #pragma unroll
    for (int k = 0; k < CC; ++k)
        ob[(size_t)k * HWSZ] = (y[k] + dx[k] * umask) * alive;
}

extern "C" void kernel_launch(void* const* d_in, const int* in_sizes, int n_in,
                              void* d_out, int out_size, void* d_ws, size_t ws_size,
                              hipStream_t stream)
{
    const float* x     = (const float*)d_in[0];
    const float* noise = (const float*)d_in[1];
    const float* w1w   = (const float*)d_in[2];
    const float* w1b   = (const float*)d_in[3];
    const float* w2w   = (const float*)d_in[4];
    float* out = (float*)d_out;

    const int npix = BB * HWSZ;           // 1,048,576
    const int block = 256;
    const int grid = (npix + block - 1) / block;   // 4096
    nca_fp32_kernel<<<grid, block, 0, stream>>>(x, noise, w1w, w1b, w2w, out);
}

// Round 3
// 76.809 us; speedup vs baseline: 3.5204x; 3.5204x over previous
//
#include <hip/hip_runtime.h>

// NCA update via fp16 MFMA.
// GEMM1: H[o][pix] = W1[o][c] * Y[pix][c] + b[o]   (per 16-px tile: 12x mfma 16x16x32)
// GEMM2: dx[ch][pix] = W2[ch][o] * relu(H)[pix][o] (6x mfma, H passes lane-locally)
// Perception Y built with column-sum + shfl neighbor exchange (circular).

#define HH 512
#define WW 512
#define CC 16
#define HID 192
#define NT 32
#define HW (HH * WW)

typedef _Float16 half8 __attribute__((ext_vector_type(8)));
typedef __fp16   fp16x2 __attribute__((ext_vector_type(2)));
typedef float    f32x4 __attribute__((ext_vector_type(4)));

__device__ __forceinline__ float shfl64(float v, int srcLane) {
    return __shfl(v, srcLane, 64);
}

__global__ __launch_bounds__(256, 2) void nca_mfma_kernel(
    const float* __restrict__ x,
    const float* __restrict__ noise,
    const float* __restrict__ w1w,
    const float* __restrict__ w1b,
    const float* __restrict__ w2w,
    float* __restrict__ out)
{
    __shared__ __align__(16) float bl[HID];
    const int tid  = threadIdx.x;
    const int lane = tid & 63;
    const int wid  = tid >> 6;
    const int p    = lane & 15;   // pixel-in-tile / matrix row-col index
    const int gq   = lane >> 4;   // fragment k-group

    // XCD-aware swizzle: 512 blocks -> 8 chunks of 64 consecutive blocks
    const int bid = blockIdx.x;
    const int lin = (bid & 7) * 64 + (bid >> 3);
    const int gr  = lin * 4 + wid;          // global row id 0..2047
    const int b   = gr >> 9;
    const int i   = gr & 511;

    // stage bias to LDS
    for (int k = tid; k < HID; k += 256) bl[k] = w1b[k];
    __syncthreads();

    // resident W1 A-fragments: lane holds W1[o=16t+p][c=8*gq+e]
    half8 w1f[12];
    #pragma unroll
    for (int t = 0; t < 12; ++t) {
        const float* src = w1w + (16 * t + p) * 32 + 8 * gq;
        #pragma unroll
        for (int e = 0; e < 8; ++e) w1f[t][e] = (_Float16)src[e];
    }
    // resident W2 A-fragments with sigma(f,g,e)=16*(2f+(e>>2))+4g+(e&3)
    half8 w2f[6];
    #pragma unroll
    for (int f = 0; f < 6; ++f) {
        const float* s0 = w2w + p * HID + 32 * f + 4 * gq;
        #pragma unroll
        for (int e = 0; e < 4; ++e) {
            w2f[f][e]     = (_Float16)s0[e];
            w2f[f][4 + e] = (_Float16)s0[16 + e];
        }
    }

    const int im = (i == 0) ? HH - 1 : i - 1;
    const int ip = (i == HH - 1) ? 0 : i + 1;
    const float* xb  = x + (size_t)b * CC * HW;
    const int    cb  = 8 * (gq & 1);          // x-channel base for this lane
    const float* xcb = xb + (size_t)cb * HW;
    const int rT = im * WW, rM = i * WW, rB = ip * WW;

    // column-sums (top+mid+bot) for 8 channels + ch3 column-max, at column `col`
    auto loadCS = [&](int col, float cs[8], float mid[8], float& cm) {
        #pragma unroll
        for (int e = 0; e < 8; ++e) {
            const float* pe = xcb + (size_t)e * HW;
            const float t_ = pe[rT + col];
            const float m_ = pe[rM + col];
            const float b_ = pe[rB + col];
            cs[e]  = t_ + m_ + b_;
            mid[e] = m_;
            if (e == 3) cm = fmaxf(fmaxf(t_, m_), b_);
        }
    };

    float csA[8], csB[8], csC[8], midB[8], midC[8], csF[8];
    float cmA = 0.f, cmB, cmC, cmF;
    float hLcs[8], hLcm, dumMid[8];

    loadCS(WW - 1, hLcs, dumMid, hLcm);     // left wrap halo (column 511)
    loadCS(p, csB, midB, cmB);              // tile 0
    #pragma unroll
    for (int e = 0; e < 8; ++e) csF[e] = csB[e];
    cmF = cmB;

    const float* nrow = noise + (size_t)b * HW + rM;
    float* ob = out + (size_t)b * CC * HW;
    const f32x4* blv = (const f32x4*)bl;

    #pragma unroll 1
    for (int t = 0; t < NT; ++t) {
        if (t < NT - 1) {
            loadCS(16 * (t + 1) + p, csC, midC, cmC);
        } else {
            #pragma unroll
            for (int e = 0; e < 8; ++e) csC[e] = csF[e];  // wrap to tile 0
            cmC = cmF;
        }

        // ---- perception Y fragment: lane holds Y[pix=p][c_y=8*gq+e] ----
        const bool isCenter = (gq < 2);
        float yv[8];
        #pragma unroll
        for (int e = 0; e < 8; ++e) {
            float lft  = __shfl_up(csB[e], 1, 64);
            const float patL = (t == 0) ? hLcs[e] : shfl64(csA[e], lane | 15);
            if (p == 0) lft = patL;
            float rgt  = __shfl_down(csB[e], 1, 64);
            const float patR = shfl64(csC[e], lane & 48);
            if (p == 15) rgt = patR;
            const float S9  = lft + csB[e] + rgt;
            const float lap = 9.0f * midB[e] - S9;
            yv[e] = isCenter ? midB[e] : lap;
        }
        union { half8 v; fp16x2 f2[4]; } yf;
        #pragma unroll
        for (int e = 0; e < 4; ++e)
            yf.f2[e] = __builtin_amdgcn_cvt_pkrtz(yv[2 * e], yv[2 * e + 1]);

        // ---- alive mask (3x3 circular max of channel 3) ----
        float ml = __shfl_up(cmB, 1, 64);
        const float pml = (t == 0) ? hLcm : shfl64(cmA, lane | 15);
        if (p == 0) ml = pml;
        float mr = __shfl_down(cmB, 1, 64);
        const float pmr = shfl64(cmC, lane & 48);
        if (p == 15) mr = pmr;
        const float rmax  = fmaxf(fmaxf(ml, cmB), mr);
        const float av    = shfl64(rmax, lane & 15);
        const float alive = (av > 0.1f) ? 1.0f : 0.0f;

        const int col = 16 * t + p;
        const float nz = nrow[col];
        const float um = floorf(nz + 0.5f);

        // ---- GEMM1 + relu + GEMM2 (H stays lane-local) ----
        f32x4 acc2a = {0.f, 0.f, 0.f, 0.f}, acc2b = {0.f, 0.f, 0.f, 0.f};
        #pragma unroll
        for (int f = 0; f < 6; ++f) {
            const f32x4 ba = blv[8 * f + gq];
            const f32x4 bb = blv[8 * f + 4 + gq];
            const f32x4 a1 = __builtin_amdgcn_mfma_f32_16x16x32_f16(w1f[2 * f],     yf.v, ba, 0, 0, 0);
            const f32x4 a2 = __builtin_amdgcn_mfma_f32_16x16x32_f16(w1f[2 * f + 1], yf.v, bb, 0, 0, 0);
            union { half8 v; fp16x2 f2[4]; } hf;
            hf.f2[0] = __builtin_amdgcn_cvt_pkrtz(fmaxf(a1[0], 0.f), fmaxf(a1[1], 0.f));
            hf.f2[1] = __builtin_amdgcn_cvt_pkrtz(fmaxf(a1[2], 0.f), fmaxf(a1[3], 0.f));
            hf.f2[2] = __builtin_amdgcn_cvt_pkrtz(fmaxf(a2[0], 0.f), fmaxf(a2[1], 0.f));
            hf.f2[3] = __builtin_amdgcn_cvt_pkrtz(fmaxf(a2[2], 0.f), fmaxf(a2[3], 0.f));
            if (f & 1) acc2b = __builtin_amdgcn_mfma_f32_16x16x32_f16(w2f[f], hf.v, acc2b, 0, 0, 0);
            else       acc2a = __builtin_amdgcn_mfma_f32_16x16x32_f16(w2f[f], hf.v, acc2a, 0, 0, 0);
        }

        // ---- blend + store: lane holds dx[ch=4*gq+r][pix=p] ----
        #pragma unroll
        for (int r = 0; r < 4; ++r) {
            const size_t off = (size_t)(4 * gq + r) * HW + (size_t)rM + col;
            const float dx = acc2a[r] + acc2b[r];
            ob[off] = (xb[off] + dx * um) * alive;
        }

        // rotate pipeline
        #pragma unroll
        for (int e = 0; e < 8; ++e) { csA[e] = csB[e]; csB[e] = csC[e]; midB[e] = midC[e]; }
        cmA = cmB; cmB = cmC;
    }
}

extern "C" void kernel_launch(void* const* d_in, const int* in_sizes, int n_in,
                              void* d_out, int out_size, void* d_ws, size_t ws_size,
                              hipStream_t stream)
{
    const float* x     = (const float*)d_in[0];
    const float* noise = (const float*)d_in[1];
    const float* w1w   = (const float*)d_in[2];
    const float* w1b   = (const float*)d_in[3];
    const float* w2w   = (const float*)d_in[4];
    float* out = (float*)d_out;

    nca_mfma_kernel<<<512, 256, 0, stream>>>(x, noise, w1w, w1b, w2w, out);
}